// Round 5
// baseline (7608.584 us; speedup 1.0000x reference)
//
#include <hip/hip_runtime.h>
#include <hip/hip_bf16.h>
#include <math.h>

#define L_LAYERS 4
#define BIMG 8
#define PATCH_H 37
#define PATCH_W 37
#define PP 1369
#define DD 1024
#define JJ 768
#define HOUT 518
#define WOUT 518
#define PPAD 1408   // 11 * 128
#define NPAIR 28
#define ZPAIR (L_LAYERS * NPAIR)          // 112
#define RFSZ  ((size_t)L_LAYERS * BIMG * PPAD * DD)    // bytes (fp8) = 46,137,344
#define NRMSZ ((size_t)L_LAYERS * BIMG * PPAD)         // floats
#define MINDSZ ((size_t)L_LAYERS * BIMG * BIMG * PP)   // uints

typedef float floatx4  __attribute__((ext_vector_type(4)));
typedef float floatx16 __attribute__((ext_vector_type(16)));
typedef int   intx8    __attribute__((ext_vector_type(8)));
typedef long  longx4   __attribute__((ext_vector_type(4)));
#define MXSC 0x7f7f7f7f   // 4x E8M0 = 127 -> scale 1.0

// ---- software OCP e4m3fn encode/decode (RTNE) ------------------------------
__device__ __forceinline__ unsigned int f2e4m3(float v) {
  unsigned int b = __float_as_uint(v);
  unsigned int sign = (b >> 24) & 0x80u;
  float mag = fabsf(v);
  unsigned int code;
  if (mag >= 0.015625f) {                       // normal (exp >= -6)
    unsigned int mb = __float_as_uint(mag);
    mb = mb + 0x0007ffffu + ((mb >> 20) & 1u);  // RTNE to 3 mantissa bits
    code = (((mb >> 23) - 120u) << 3) | ((mb >> 20) & 7u);
  } else {                                      // denormal: quantum 2^-9
    code = (unsigned int)__float2int_rn(mag * 512.0f);
  }
  return code | sign;
}
__device__ __forceinline__ float e4m3tof(unsigned int c) {
  unsigned int em = c & 0x7fu;
  float m;
  if (em >= 8u) m = __uint_as_float((((em >> 3) + 120u) << 23) | ((em & 7u) << 20));
  else          m = (float)em * 0.001953125f;
  return (c & 0x80u) ? -m : m;
}

// rf physical byte swizzle, baked at store time:
// within each 64B K-chunk of patch-row p:  granule g (16B) -> g ^ ((p>>2)&3),
// half h (8B) -> h ^ ((p>>1)&1).  K3 stages linearly and compensates on its
// ds_read_b64 fragment reads -> bank-conflict-free.
__device__ __forceinline__ int rf_swz(int p, int d) {
  return (d & ~63) |
         ((((d >> 4) & 3) ^ ((p >> 2) & 3)) << 4) |
         ((((d >> 3) & 1) ^ ((p >> 1) & 1)) << 3) |
         (d & 7);
}

// async global->LDS, 16B per lane; LDS dest = wave-uniform base + lane*16
__device__ __forceinline__ void gload_lds16(const void* gptr, void* lptr) {
  __builtin_amdgcn_global_load_lds(
      (const __attribute__((address_space(1))) unsigned int*)gptr,
      (__attribute__((address_space(3))) unsigned int*)lptr, 16, 0, 0);
}

// fragment assembly: 4 x ds_read_b64 into an ext_vector (register-only;
// NO union type-pun -- a union here goes to scratch and costs ~20 GB of
// HBM traffic, R4 post-mortem), then bit_cast to the v8i32 MFMA operand.
__device__ __forceinline__ intx8 loadfrag(const unsigned char* basep, int roff,
                                          int off0, int off1, int off2, int off3) {
  longx4 t;
  t[0] = *(const long*)(basep + roff + off0);
  t[1] = *(const long*)(basep + roff + off1);
  t[2] = *(const long*)(basep + roff + off2);
  t[3] = *(const long*)(basep + roff + off3);
  return __builtin_bit_cast(intx8, t);
}

// ---------------------------------------------------------------------------
// K1: per-(l,b) mean of features (float32).  grid (43, 32), block 256.
__global__ __launch_bounds__(256) void k1_mu(const float* __restrict__ x,
                                             float* __restrict__ mu_acc) {
  const int lb = blockIdx.y;
  const float* base = x + (size_t)lb * PP * DD;
  const int N4 = PP * DD / 4;
  float s = 0.0f;
  for (int idx = blockIdx.x * 256 + threadIdx.x; idx < N4; idx += gridDim.x * 256) {
    float4 u = *(const float4*)(base + (size_t)idx * 4);
    s += u.x + u.y + u.z + u.w;
  }
  for (int off = 1; off < 64; off <<= 1) s += __shfl_xor(s, off, 64);
  __shared__ float red[4];
  if ((threadIdx.x & 63) == 0) red[threadIdx.x >> 6] = s;
  __syncthreads();
  if (threadIdx.x == 0)
    atomicAdd(&mu_acc[lb], red[0] + red[1] + red[2] + red[3]);
}

// ---------------------------------------------------------------------------
// shared finisher: subtract cnt*mu, block-L2-normalize, x16, fp8-encode, store
__device__ __forceinline__ void finish_r(float s0, float s1, float s2, float s3,
                                         float cm, unsigned char* dst, float* nrmdst,
                                         int tid, float* red) {
  s0 -= cm; s1 -= cm; s2 -= cm; s3 -= cm;
  float sq = s0 * s0 + s1 * s1 + s2 * s2 + s3 * s3;
  for (int off = 1; off < 64; off <<= 1) sq += __shfl_xor(sq, off, 64);
  __syncthreads();
  if ((tid & 63) == 0) red[tid >> 6] = sq;
  __syncthreads();
  const float rn16 = rsqrtf(red[0] + red[1] + red[2] + red[3]) * 16.0f;
  unsigned int c0 = f2e4m3(s0 * rn16), c1 = f2e4m3(s1 * rn16);
  unsigned int c2 = f2e4m3(s2 * rn16), c3 = f2e4m3(s3 * rn16);
  uchar4 o; o.x = (unsigned char)c0; o.y = (unsigned char)c1;
  o.z = (unsigned char)c2; o.w = (unsigned char)c3;
  *(uchar4*)dst = o;
  float q0 = e4m3tof(c0), q1 = e4m3tof(c1), q2 = e4m3tof(c2), q3 = e4m3tof(c3);
  float nq = q0 * q0 + q1 * q1 + q2 * q2 + q3 * q3;
  for (int off = 1; off < 64; off <<= 1) nq += __shfl_xor(nq, off, 64);
  __syncthreads();
  if ((tid & 63) == 0) red[tid >> 6] = nq;
  __syncthreads();
  if (tid == 0) *nrmdst = red[0] + red[1] + red[2] + red[3];
}

// K2f: fused pool for r=1,3,5 from one 5x5 read.  grid (PPAD, 32), block 256.
__global__ __launch_bounds__(256) void k2_pool3(const float* __restrict__ x,
                                                const float* __restrict__ mu_acc,
                                                unsigned char* __restrict__ rf,
                                                float* __restrict__ nrm) {
  const int p  = blockIdx.x;
  const int lb = blockIdx.y;
  const int tid = threadIdx.x;
  const int d0 = tid * 4;
  if (p >= PP) {
    const size_t zoff = ((size_t)lb * PPAD + p) * DD + d0;
    uchar4 z; z.x = 0; z.y = 0; z.z = 0; z.w = 0;
    for (int r = 0; r < 3; r++) {
      *(uchar4*)(rf + r * RFSZ + zoff) = z;
      if (tid == 0) nrm[r * NRMSZ + (size_t)lb * PPAD + p] = 0.0f;
    }
    return;
  }
  // store at physical (bank-swizzled) offset
  const size_t outoff = ((size_t)lb * PPAD + p) * DD + rf_swz(p, d0);
  const float mu = mu_acc[lb] * (1.0f / ((float)PP * (float)DD));
  const int ph = p / PATCH_W, pw = p % PATCH_W;
  float a5[4] = {0, 0, 0, 0}, a3[4] = {0, 0, 0, 0}, a1[4] = {0, 0, 0, 0};
  int c5 = 0, c3 = 0;
  for (int dy = -2; dy <= 2; dy++) {
    int qh = ph + dy; if (qh < 0 || qh >= PATCH_H) continue;
    for (int dx = -2; dx <= 2; dx++) {
      int qw = pw + dx; if (qw < 0 || qw >= PATCH_W) continue;
      const float* src = x + ((size_t)lb * PP + qh * PATCH_W + qw) * DD + d0;
      float4 u = *(const float4*)src;
      a5[0] += u.x; a5[1] += u.y; a5[2] += u.z; a5[3] += u.w; c5++;
      if (dy >= -1 && dy <= 1 && dx >= -1 && dx <= 1) {
        a3[0] += u.x; a3[1] += u.y; a3[2] += u.z; a3[3] += u.w; c3++;
        if (dy == 0 && dx == 0) { a1[0] = u.x; a1[1] = u.y; a1[2] = u.z; a1[3] = u.w; }
      }
    }
  }
  __shared__ float red[4];
  const size_t noff = (size_t)lb * PPAD + p;
  finish_r(a1[0], a1[1], a1[2], a1[3], mu, rf + outoff, nrm + noff, tid, red);
  finish_r(a3[0], a3[1], a3[2], a3[3], (float)c3 * mu, rf + RFSZ + outoff,
           nrm + NRMSZ + noff, tid, red);
  finish_r(a5[0], a5[1], a5[2], a5[3], (float)c5 * mu, rf + 2 * RFSZ + outoff,
           nrm + 2 * NRMSZ + noff, tid, red);
}

// K2s: single-r pool (fallback path).  grid (PPAD, 32), block 256.
__global__ __launch_bounds__(256) void k2_pool(const float* __restrict__ x,
                                               const float* __restrict__ mu_acc,
                                               unsigned char* __restrict__ rf,
                                               float* __restrict__ nrm, int r) {
  const int p  = blockIdx.x;
  const int lb = blockIdx.y;
  const int tid = threadIdx.x;
  const int d0 = tid * 4;
  if (p >= PP) {
    const size_t zoff = ((size_t)lb * PPAD + p) * DD + d0;
    uchar4 z; z.x = 0; z.y = 0; z.z = 0; z.w = 0;
    *(uchar4*)(rf + zoff) = z;
    if (tid == 0) nrm[(size_t)lb * PPAD + p] = 0.0f;
    return;
  }
  const size_t outoff = ((size_t)lb * PPAD + p) * DD + rf_swz(p, d0);
  const float mu = mu_acc[lb] * (1.0f / ((float)PP * (float)DD));
  const int ph = p / PATCH_W, pw = p % PATCH_W;
  const int pad = r >> 1;
  float s0 = 0, s1 = 0, s2 = 0, s3 = 0;
  int cnt = 0;
  for (int dy = -pad; dy <= pad; dy++) {
    int qh = ph + dy; if (qh < 0 || qh >= PATCH_H) continue;
    for (int dx = -pad; dx <= pad; dx++) {
      int qw = pw + dx; if (qw < 0 || qw >= PATCH_W) continue;
      cnt++;
      const float* src = x + ((size_t)lb * PP + qh * PATCH_W + qw) * DD + d0;
      float4 u = *(const float4*)src;
      s0 += u.x; s1 += u.y; s2 += u.z; s3 += u.w;
    }
  }
  __shared__ float red[4];
  finish_r(s0, s1, s2, s3, (float)cnt * mu, rf + outoff,
           nrm + (size_t)lb * PPAD + p, tid, red);
}

// ---------------------------------------------------------------------------
// K3: per (rsel, l, pair i<j): S = rf_i @ rf_j^T (fp8, S = 256*dot).
// 128x128 tile, 4 waves x 2x2 MFMA_SCALE 32x32x64 fp8 (unit E8M0 scales ->
// bit-equivalent to plain fp8 dot, 2.3x the 16x16x32 instruction rate),
// BK=64, pre-swizzled rf (linear global_load_lds staging; ds_read_b64
// fragment reads compensate the swizzle -> conflict-free).
// Schedule: double-buffered LDS, counted s_waitcnt vmcnt(4) + raw s_barrier,
// XCD-chunk block swizzle (L2-resident pair panels).
// Fused epilogue: row/col max of (2S - n_other) via atomicMax(uint(v+1024)).
// grid (121*nz), block 256, 3 blk/CU.
__global__ __launch_bounds__(256, 3) void k3_pairdots(const unsigned char* __restrict__ rf,
                                                      const float* __restrict__ nrm,
                                                      unsigned int* __restrict__ mind) {
  // T1: XCD-chunk bijective swizzle (gridDim.x divisible by 8; chunks cover
  // whole pairs since 5082 = 42*121, 1694 = 14*121).
  const unsigned int cpx = gridDim.x >> 3;
  const unsigned int wid = (blockIdx.x & 7) * cpx + (blockIdx.x >> 3);
  const int z  = wid / 121;
  const int rm = wid % 121;
  const int ty = rm / 11;        // col tile
  const int tx = rm % 11;        // row tile

  const int rsel = z / ZPAIR;
  const int zz   = z % ZPAIR;
  const int l = zz / NPAIR;
  int rem = zz % NPAIR;
  int i = 0, span = BIMG - 1;
  while (rem >= span) { rem -= span; span--; i++; }
  const int j = i + 1 + rem;

  const unsigned char* rfr = rf + (size_t)rsel * RFSZ;
  const int rowbase = tx * 128;
  const int colbase = ty * 128;
  const unsigned char* A  = rfr + ((size_t)(l * BIMG + i) * PPAD + rowbase) * DD;
  const unsigned char* Bp = rfr + ((size_t)(l * BIMG + j) * PPAD + colbase) * DD;

  __shared__ __align__(16) unsigned char lA[2][128 * 64];  // 2 x 8 KB
  __shared__ __align__(16) unsigned char lB[2][128 * 64];

  const int tid  = threadIdx.x;
  const int lane = tid & 63;
  const int wave = tid >> 6;
  const int ls   = lane & 31;          // row within 32-row MFMA tile
  const int khg  = (lane >> 5) * 2;    // logical 16B-granule base of K-chunk
  const int gsw  = (ls >> 2) & 3;      // granule swizzle (matches rf_swz)
  const int hsw  = (ls >> 1) & 1;      // 8B-half swizzle
  // physical byte offsets (within the 64B LDS row) of the 4 logical 8B pieces
  const int off0 = ((khg ^ gsw) << 4)       | (hsw << 3);
  const int off1 = ((khg ^ gsw) << 4)       | ((1 ^ hsw) << 3);
  const int off2 = (((khg + 1) ^ gsw) << 4) | (hsw << 3);
  const int off3 = (((khg + 1) ^ gsw) << 4) | ((1 ^ hsw) << 3);

  const int wr = (wave >> 1) * 64;
  const int wc = (wave & 1) * 64;
  const int rA0 = (wr + ls) * 64,      rA1 = (wr + 32 + ls) * 64;
  const int rB0 = (wc + ls) * 64,      rB1 = (wc + 32 + ls) * 64;

  floatx16 acc[2][2];
#pragma unroll
  for (int a = 0; a < 2; a++)
#pragma unroll
    for (int b = 0; b < 2; b++)
#pragma unroll
      for (int r = 0; r < 16; r++) acc[a][b][r] = 0.0f;

  // staging: lane covers row = wave*32 + lane>>2 [+16], granule lane&3.
  // rf is pre-swizzled, so this is a plain linear copy.
  const int r0  = wave * 32 + (lane >> 2);
  const size_t goff = (size_t)r0 * DD + (lane & 3) * 16;   // same for A and B
  const int woff = wave * 2048;

  // prologue: stage tile 0 into buffer 0 (4 outstanding vm ops)
  gload_lds16(A + goff, lA[0] + woff);
  gload_lds16(A + goff + 16 * DD, lA[0] + woff + 1024);
  gload_lds16(Bp + goff, lB[0] + woff);
  gload_lds16(Bp + goff + 16 * DD, lB[0] + woff + 1024);

  for (int t = 0; t < 15; ++t) {
    const int cur = t & 1;
    // issue next tile's loads into the other buffer (outstanding -> 8)
    const int k1 = (t + 1) << 6;
    gload_lds16(A + goff + k1, lA[cur ^ 1] + woff);
    gload_lds16(A + goff + 16 * DD + k1, lA[cur ^ 1] + woff + 1024);
    gload_lds16(Bp + goff + k1, lB[cur ^ 1] + woff);
    gload_lds16(Bp + goff + 16 * DD + k1, lB[cur ^ 1] + woff + 1024);
    // counted wait: tile t's 4 loads landed; tile t+1's 4 keep flying
    asm volatile("s_waitcnt vmcnt(4)" ::: "memory");
    __builtin_amdgcn_s_barrier();          // all waves' tile-t data resident
    __builtin_amdgcn_sched_barrier(0);
    {
      const unsigned char* cA = lA[cur];
      const unsigned char* cB = lB[cur];
      intx8 a0 = loadfrag(cA, rA0, off0, off1, off2, off3);
      intx8 a1 = loadfrag(cA, rA1, off0, off1, off2, off3);
      intx8 b0 = loadfrag(cB, rB0, off0, off1, off2, off3);
      intx8 b1 = loadfrag(cB, rB1, off0, off1, off2, off3);
      acc[0][0] = __builtin_amdgcn_mfma_scale_f32_32x32x64_f8f6f4(
          a0, b0, acc[0][0], 0, 0, 0, MXSC, 0, MXSC);
      acc[0][1] = __builtin_amdgcn_mfma_scale_f32_32x32x64_f8f6f4(
          a0, b1, acc[0][1], 0, 0, 0, MXSC, 0, MXSC);
      acc[1][0] = __builtin_amdgcn_mfma_scale_f32_32x32x64_f8f6f4(
          a1, b0, acc[1][0], 0, 0, 0, MXSC, 0, MXSC);
      acc[1][1] = __builtin_amdgcn_mfma_scale_f32_32x32x64_f8f6f4(
          a1, b1, acc[1][1], 0, 0, 0, MXSC, 0, MXSC);
    }
    __builtin_amdgcn_sched_barrier(0);
    __builtin_amdgcn_s_barrier();          // all waves done reading buf[cur]
  }
  // tail t=15: only its own 4 loads outstanding
  asm volatile("s_waitcnt vmcnt(0)" ::: "memory");
  __builtin_amdgcn_s_barrier();
  __builtin_amdgcn_sched_barrier(0);
  {
    const unsigned char* cA = lA[1];
    const unsigned char* cB = lB[1];
    intx8 a0 = loadfrag(cA, rA0, off0, off1, off2, off3);
    intx8 a1 = loadfrag(cA, rA1, off0, off1, off2, off3);
    intx8 b0 = loadfrag(cB, rB0, off0, off1, off2, off3);
    intx8 b1 = loadfrag(cB, rB1, off0, off1, off2, off3);
    acc[0][0] = __builtin_amdgcn_mfma_scale_f32_32x32x64_f8f6f4(
        a0, b0, acc[0][0], 0, 0, 0, MXSC, 0, MXSC);
    acc[0][1] = __builtin_amdgcn_mfma_scale_f32_32x32x64_f8f6f4(
        a0, b1, acc[0][1], 0, 0, 0, MXSC, 0, MXSC);
    acc[1][0] = __builtin_amdgcn_mfma_scale_f32_32x32x64_f8f6f4(
        a1, b0, acc[1][0], 0, 0, 0, MXSC, 0, MXSC);
    acc[1][1] = __builtin_amdgcn_mfma_scale_f32_32x32x64_f8f6f4(
        a1, b1, acc[1][1], 0, 0, 0, MXSC, 0, MXSC);
  }

  const float* nI = nrm + rsel * NRMSZ + (size_t)(l * BIMG + i) * PPAD;
  const float* nJ = nrm + rsel * NRMSZ + (size_t)(l * BIMG + j) * PPAD;
  unsigned int* mrow = mind + rsel * MINDSZ + ((size_t)(l * BIMG + i) * BIMG + j) * PP;
  unsigned int* mcol = mind + rsel * MINDSZ + ((size_t)(l * BIMG + j) * BIMG + i) * PP;

  const int rhalf = 4 * (lane >> 5);   // +4 row offset for upper lane half

  // row-max of (2S - n_j): C/D layout col=lane&31, row=(reg&3)+8*(reg>>2)+rhalf
#pragma unroll
  for (int mt = 0; mt < 2; mt++) {
#pragma unroll
    for (int reg = 0; reg < 16; reg++) {
      const int gr = rowbase + wr + mt * 32 + (reg & 3) + 8 * (reg >> 2) + rhalf;
      float v = -1e30f;
#pragma unroll
      for (int nt = 0; nt < 2; nt++) {
        const int gc = colbase + wc + nt * 32 + ls;
        if (gc < PP) v = fmaxf(v, 2.0f * acc[mt][nt][reg] - nJ[gc]);
      }
      for (int off = 1; off < 32; off <<= 1) v = fmaxf(v, __shfl_xor(v, off, 64));
      if (ls == 0 && gr < PP)
        atomicMax(mrow + gr, __float_as_uint(v + 1024.0f));
    }
  }
  // col-max of (2S - n_i)
#pragma unroll
  for (int nt = 0; nt < 2; nt++) {
    const int gc = colbase + wc + nt * 32 + ls;
    float v = -1e30f;
#pragma unroll
    for (int mt = 0; mt < 2; mt++) {
#pragma unroll
      for (int reg = 0; reg < 16; reg++) {
        const int gr = rowbase + wr + mt * 32 + (reg & 3) + 8 * (reg >> 2) + rhalf;
        if (gr < PP) v = fmaxf(v, 2.0f * acc[mt][nt][reg] - nI[gr]);
      }
    }
    v = fmaxf(v, __shfl_xor(v, 32, 64));
    if (lane < 32 && gc < PP)
      atomicMax(mcol + gc, __float_as_uint(v + 1024.0f));
  }
}

// ---------------------------------------------------------------------------
// K4: per (i,p): over nr r-buffers and L layers, d2=(n_own - max(2S-n_other))/256,
// dist=sqrt; mean of 2 smallest over b!=i; accumulate into scores.
__global__ void k4_scores(const unsigned int* __restrict__ mind,
                          const float* __restrict__ nrm,
                          float* __restrict__ scores, int nr) {
  const int idx = blockIdx.x * 256 + threadIdx.x;
  if (idx >= BIMG * PP) return;
  const int i = idx / PP, p = idx % PP;
  float accum = 0.0f;
  for (int r = 0; r < nr; r++) {
    for (int l = 0; l < L_LAYERS; l++) {
      const float n_own = nrm[r * NRMSZ + (size_t)(l * BIMG + i) * PPAD + p];
      float m1 = 1e30f, m2 = 1e30f;
      for (int b = 0; b < BIMG; b++) {
        if (b == i) continue;
        const unsigned int enc =
            mind[r * MINDSZ + ((size_t)(l * BIMG + i) * BIMG + b) * PP + p];
        const float val = __uint_as_float(enc) - 1024.0f;
        const float d2 = fmaxf((n_own - val) * (1.0f / 256.0f), 1e-12f);
        const float dist = sqrtf(d2);
        if (dist < m1) { m2 = m1; m1 = dist; }
        else if (dist < m2) { m2 = dist; }
      }
      accum += 0.5f * (m1 + m2);
    }
  }
  scores[idx] += accum * (1.0f / (float)(L_LAYERS * 3));
}

// ---------------------------------------------------------------------------
__global__ void k5_imgmax(const float* __restrict__ scores, float* __restrict__ img) {
  const int i = blockIdx.x;
  float m = -1e30f;
  for (int p = threadIdx.x; p < PP; p += 256) m = fmaxf(m, scores[i * PP + p]);
  for (int off = 1; off < 64; off <<= 1) m = fmaxf(m, __shfl_xor(m, off, 64));
  __shared__ float red[4];
  if ((threadIdx.x & 63) == 0) red[threadIdx.x >> 6] = m;
  __syncthreads();
  if (threadIdx.x == 0)
    img[i] = fmaxf(fmaxf(red[0], red[1]), fmaxf(red[2], red[3]));
}

// ---------------------------------------------------------------------------
__global__ void k6_final(const float* __restrict__ cls,
                         const float* __restrict__ img,
                         float* __restrict__ out) {
  __shared__ float norms[BIMG];
  __shared__ float sim[BIMG][BIMG];
  const int t = threadIdx.x;
  if (t < BIMG) {
    float s = 0;
    for (int d = 0; d < JJ; d++) { float v = cls[t * JJ + d]; s += v * v; }
    norms[t] = sqrtf(s);
  }
  __syncthreads();
  {
    const int ii = t >> 3, jj = t & 7;
    float s = 0;
    for (int d = 0; d < JJ; d++) s += cls[ii * JJ + d] * cls[jj * JJ + d];
    sim[ii][jj] = s / (norms[ii] * norms[jj]);
  }
  __syncthreads();
  if (t < BIMG) {
    float v[8]; int id[8];
    for (int a = 0; a < 8; a++) { v[a] = sim[t][a]; id[a] = a; }
    for (int a = 0; a < 8; a++) {
      int best = a;
      for (int b = a + 1; b < 8; b++) if (v[b] > v[best]) best = b;
      float tv = v[a]; v[a] = v[best]; v[best] = tv;
      int ti = id[a]; id[a] = id[best]; id[best] = ti;
    }
    float res = 0;
    for (int k = 1; k <= 3; k++) {
      float num = 0, den = 0;
      for (int a = 0; a < k; a++) { num += v[a] * img[id[a]]; den += v[a]; }
      res += num / den;
    }
    out[t] = res * (1.0f / 3.0f);
  }
}

// ---------------------------------------------------------------------------
__global__ void k7_pixel(const float* __restrict__ scores,
                         float* __restrict__ out) {
  const int idx = blockIdx.x * 256 + threadIdx.x;
  if (idx >= BIMG * HOUT * WOUT) return;
  const int b = idx / (HOUT * WOUT);
  const int rem = idx % (HOUT * WOUT);
  const int Y = rem / WOUT, X = rem % WOUT;
  const float sy = (float)(PATCH_H - 1) / (float)(HOUT - 1);
  const float sx = (float)(PATCH_W - 1) / (float)(WOUT - 1);
  float py = (float)Y * sy;
  float px = (float)X * sx;
  int y0 = (int)floorf(py); y0 = min(max(y0, 0), PATCH_H - 1);
  int x0 = (int)floorf(px); x0 = min(max(x0, 0), PATCH_W - 1);
  const int y1 = min(y0 + 1, PATCH_H - 1);
  const int x1 = min(x0 + 1, PATCH_W - 1);
  const float wy = py - (float)y0, wx = px - (float)x0;
  const float* sc = scores + (size_t)b * PP;
  const float v =
      (1.f - wy) * ((1.f - wx) * sc[y0 * PATCH_W + x0] + wx * sc[y0 * PATCH_W + x1]) +
      wy         * ((1.f - wx) * sc[y1 * PATCH_W + x0] + wx * sc[y1 * PATCH_W + x1]);
  out[8 + idx] = v;
}

// ---------------------------------------------------------------------------
extern "C" void kernel_launch(void* const* d_in, const int* in_sizes, int n_in,
                              void* d_out, int out_size, void* d_ws, size_t ws_size,
                              hipStream_t stream) {
  const float* feat = (const float*)d_in[0];  // (4,8,1369,1024) f32
  const float* cls  = (const float*)d_in[1];  // (8,768) f32
  float* out = (float*)d_out;

  const size_t need_fused = 3 * RFSZ + 3 * MINDSZ * 4 + 3 * NRMSZ * 4 +
                            (size_t)BIMG * PP * 4 + 1024;
  const bool fused = ws_size >= need_fused;

  char* ws = (char*)d_ws;
  size_t off = 0;
  unsigned char* rf = (unsigned char*)(ws + off);
  off += (fused ? 3 : 1) * RFSZ;
  unsigned int* mind = (unsigned int*)(ws + off);
  off += (fused ? 3 : 1) * MINDSZ * 4;
  float* nrm = (float*)(ws + off);
  off += (fused ? 3 : 1) * NRMSZ * 4;
  float* scores = (float*)(ws + off);
  off += (size_t)BIMG * PP * 4;
  float* mu_acc = (float*)(ws + off);
  off += 32 * 4;
  float* img = (float*)(ws + off);
  off += 8 * 4;

  hipMemsetAsync(mu_acc, 0, 32 * 4, stream);
  hipMemsetAsync(scores, 0, (size_t)BIMG * PP * 4, stream);
  k1_mu<<<dim3(43, 32), 256, 0, stream>>>(feat, mu_acc);

  if (fused) {
    k2_pool3<<<dim3(PPAD, 32), 256, 0, stream>>>(feat, mu_acc, rf, nrm);
    hipMemsetAsync(mind, 0, 3 * MINDSZ * 4, stream);
    k3_pairdots<<<dim3(121 * 3 * ZPAIR), 256, 0, stream>>>(rf, nrm, mind);
    k4_scores<<<(BIMG * PP + 255) / 256, 256, 0, stream>>>(mind, nrm, scores, 3);
  } else {
    const int rlist[3] = {1, 3, 5};
    for (int ri = 0; ri < 3; ri++) {
      k2_pool<<<dim3(PPAD, 32), 256, 0, stream>>>(feat, mu_acc, rf, nrm, rlist[ri]);
      hipMemsetAsync(mind, 0, MINDSZ * 4, stream);
      k3_pairdots<<<dim3(121 * ZPAIR), 256, 0, stream>>>(rf, nrm, mind);
      k4_scores<<<(BIMG * PP + 255) / 256, 256, 0, stream>>>(mind, nrm, scores, 1);
    }
  }
  k5_imgmax<<<8, 256, 0, stream>>>(scores, img);
  k6_final<<<1, 64, 0, stream>>>(cls, img, out);
  k7_pixel<<<(BIMG * HOUT * WOUT + 255) / 256, 256, 0, stream>>>(scores, out);
}

// Round 6
// 5561.156 us; speedup vs baseline: 1.3682x; 1.3682x over previous
//
#include <hip/hip_runtime.h>
#include <hip/hip_bf16.h>
#include <math.h>

#define L_LAYERS 4
#define BIMG 8
#define PATCH_H 37
#define PATCH_W 37
#define PP 1369
#define DD 1024
#define JJ 768
#define HOUT 518
#define WOUT 518
#define PPAD 1408   // 11 * 128
#define NPAIR 28
#define ZPAIR (L_LAYERS * NPAIR)          // 112
#define RFSZ  ((size_t)L_LAYERS * BIMG * PPAD * DD)    // bytes (fp8) = 46,137,344
#define NRMSZ ((size_t)L_LAYERS * BIMG * PPAD)         // floats
#define MINDSZ ((size_t)L_LAYERS * BIMG * BIMG * PP)   // uints

typedef float floatx4  __attribute__((ext_vector_type(4)));
typedef float floatx16 __attribute__((ext_vector_type(16)));
typedef int   intx8    __attribute__((ext_vector_type(8)));
typedef long  longx4   __attribute__((ext_vector_type(4)));
#define MXSC 0x7f7f7f7f   // 4x E8M0 = 127 -> scale 1.0

// ---- software OCP e4m3fn encode/decode (RTNE) ------------------------------
__device__ __forceinline__ unsigned int f2e4m3(float v) {
  unsigned int b = __float_as_uint(v);
  unsigned int sign = (b >> 24) & 0x80u;
  float mag = fabsf(v);
  unsigned int code;
  if (mag >= 0.015625f) {                       // normal (exp >= -6)
    unsigned int mb = __float_as_uint(mag);
    mb = mb + 0x0007ffffu + ((mb >> 20) & 1u);  // RTNE to 3 mantissa bits
    code = (((mb >> 23) - 120u) << 3) | ((mb >> 20) & 7u);
  } else {                                      // denormal: quantum 2^-9
    code = (unsigned int)__float2int_rn(mag * 512.0f);
  }
  return code | sign;
}
__device__ __forceinline__ float e4m3tof(unsigned int c) {
  unsigned int em = c & 0x7fu;
  float m;
  if (em >= 8u) m = __uint_as_float((((em >> 3) + 120u) << 23) | ((em & 7u) << 20));
  else          m = (float)em * 0.001953125f;
  return (c & 0x80u) ? -m : m;
}

// rf physical byte swizzle, baked at store time:
// within each 64B K-chunk of patch-row p:  granule g (16B) -> g ^ ((p>>2)&3),
// half h (8B) -> h ^ ((p>>1)&1).  K3 stages linearly and compensates on its
// ds_read_b64 fragment reads -> bank-conflict-free.
__device__ __forceinline__ int rf_swz(int p, int d) {
  return (d & ~63) |
         ((((d >> 4) & 3) ^ ((p >> 2) & 3)) << 4) |
         ((((d >> 3) & 1) ^ ((p >> 1) & 1)) << 3) |
         (d & 7);
}

// async global->LDS, 16B per lane; LDS dest = wave-uniform base + lane*16
__device__ __forceinline__ void gload_lds16(const void* gptr, void* lptr) {
  __builtin_amdgcn_global_load_lds(
      (const __attribute__((address_space(1))) unsigned int*)gptr,
      (__attribute__((address_space(3))) unsigned int*)lptr, 16, 0, 0);
}

// fragment assembly: 4 x ds_read_b64 into an ext_vector (register-only),
// then bit_cast to the v8i32 MFMA operand.
__device__ __forceinline__ intx8 loadfrag(const unsigned char* basep, int roff,
                                          int off0, int off1, int off2, int off3) {
  longx4 t;
  t[0] = *(const long*)(basep + roff + off0);
  t[1] = *(const long*)(basep + roff + off1);
  t[2] = *(const long*)(basep + roff + off2);
  t[3] = *(const long*)(basep + roff + off3);
  return __builtin_bit_cast(intx8, t);
}

// ---------------------------------------------------------------------------
// K1: per-(l,b) mean of features (float32).  grid (43, 32), block 256.
__global__ __launch_bounds__(256) void k1_mu(const float* __restrict__ x,
                                             float* __restrict__ mu_acc) {
  const int lb = blockIdx.y;
  const float* base = x + (size_t)lb * PP * DD;
  const int N4 = PP * DD / 4;
  float s = 0.0f;
  for (int idx = blockIdx.x * 256 + threadIdx.x; idx < N4; idx += gridDim.x * 256) {
    float4 u = *(const float4*)(base + (size_t)idx * 4);
    s += u.x + u.y + u.z + u.w;
  }
  for (int off = 1; off < 64; off <<= 1) s += __shfl_xor(s, off, 64);
  __shared__ float red[4];
  if ((threadIdx.x & 63) == 0) red[threadIdx.x >> 6] = s;
  __syncthreads();
  if (threadIdx.x == 0)
    atomicAdd(&mu_acc[lb], red[0] + red[1] + red[2] + red[3]);
}

// ---------------------------------------------------------------------------
// shared finisher: subtract cnt*mu, block-L2-normalize, x16, fp8-encode, store
__device__ __forceinline__ void finish_r(float s0, float s1, float s2, float s3,
                                         float cm, unsigned char* dst, float* nrmdst,
                                         int tid, float* red) {
  s0 -= cm; s1 -= cm; s2 -= cm; s3 -= cm;
  float sq = s0 * s0 + s1 * s1 + s2 * s2 + s3 * s3;
  for (int off = 1; off < 64; off <<= 1) sq += __shfl_xor(sq, off, 64);
  __syncthreads();
  if ((tid & 63) == 0) red[tid >> 6] = sq;
  __syncthreads();
  const float rn16 = rsqrtf(red[0] + red[1] + red[2] + red[3]) * 16.0f;
  unsigned int c0 = f2e4m3(s0 * rn16), c1 = f2e4m3(s1 * rn16);
  unsigned int c2 = f2e4m3(s2 * rn16), c3 = f2e4m3(s3 * rn16);
  uchar4 o; o.x = (unsigned char)c0; o.y = (unsigned char)c1;
  o.z = (unsigned char)c2; o.w = (unsigned char)c3;
  *(uchar4*)dst = o;
  float q0 = e4m3tof(c0), q1 = e4m3tof(c1), q2 = e4m3tof(c2), q3 = e4m3tof(c3);
  float nq = q0 * q0 + q1 * q1 + q2 * q2 + q3 * q3;
  for (int off = 1; off < 64; off <<= 1) nq += __shfl_xor(nq, off, 64);
  __syncthreads();
  if ((tid & 63) == 0) red[tid >> 6] = nq;
  __syncthreads();
  if (tid == 0) *nrmdst = red[0] + red[1] + red[2] + red[3];
}

// K2f: fused pool for r=1,3,5 from one 5x5 read.  grid (PPAD, 32), block 256.
__global__ __launch_bounds__(256) void k2_pool3(const float* __restrict__ x,
                                                const float* __restrict__ mu_acc,
                                                unsigned char* __restrict__ rf,
                                                float* __restrict__ nrm) {
  const int p  = blockIdx.x;
  const int lb = blockIdx.y;
  const int tid = threadIdx.x;
  const int d0 = tid * 4;
  if (p >= PP) {
    const size_t zoff = ((size_t)lb * PPAD + p) * DD + d0;
    uchar4 z; z.x = 0; z.y = 0; z.z = 0; z.w = 0;
    for (int r = 0; r < 3; r++) {
      *(uchar4*)(rf + r * RFSZ + zoff) = z;
      if (tid == 0) nrm[r * NRMSZ + (size_t)lb * PPAD + p] = 0.0f;
    }
    return;
  }
  // store at physical (bank-swizzled) offset
  const size_t outoff = ((size_t)lb * PPAD + p) * DD + rf_swz(p, d0);
  const float mu = mu_acc[lb] * (1.0f / ((float)PP * (float)DD));
  const int ph = p / PATCH_W, pw = p % PATCH_W;
  float a5[4] = {0, 0, 0, 0}, a3[4] = {0, 0, 0, 0}, a1[4] = {0, 0, 0, 0};
  int c5 = 0, c3 = 0;
  for (int dy = -2; dy <= 2; dy++) {
    int qh = ph + dy; if (qh < 0 || qh >= PATCH_H) continue;
    for (int dx = -2; dx <= 2; dx++) {
      int qw = pw + dx; if (qw < 0 || qw >= PATCH_W) continue;
      const float* src = x + ((size_t)lb * PP + qh * PATCH_W + qw) * DD + d0;
      float4 u = *(const float4*)src;
      a5[0] += u.x; a5[1] += u.y; a5[2] += u.z; a5[3] += u.w; c5++;
      if (dy >= -1 && dy <= 1 && dx >= -1 && dx <= 1) {
        a3[0] += u.x; a3[1] += u.y; a3[2] += u.z; a3[3] += u.w; c3++;
        if (dy == 0 && dx == 0) { a1[0] = u.x; a1[1] = u.y; a1[2] = u.z; a1[3] = u.w; }
      }
    }
  }
  __shared__ float red[4];
  const size_t noff = (size_t)lb * PPAD + p;
  finish_r(a1[0], a1[1], a1[2], a1[3], mu, rf + outoff, nrm + noff, tid, red);
  finish_r(a3[0], a3[1], a3[2], a3[3], (float)c3 * mu, rf + RFSZ + outoff,
           nrm + NRMSZ + noff, tid, red);
  finish_r(a5[0], a5[1], a5[2], a5[3], (float)c5 * mu, rf + 2 * RFSZ + outoff,
           nrm + 2 * NRMSZ + noff, tid, red);
}

// K2s: single-r pool (fallback path).  grid (PPAD, 32), block 256.
__global__ __launch_bounds__(256) void k2_pool(const float* __restrict__ x,
                                               const float* __restrict__ mu_acc,
                                               unsigned char* __restrict__ rf,
                                               float* __restrict__ nrm, int r) {
  const int p  = blockIdx.x;
  const int lb = blockIdx.y;
  const int tid = threadIdx.x;
  const int d0 = tid * 4;
  if (p >= PP) {
    const size_t zoff = ((size_t)lb * PPAD + p) * DD + d0;
    uchar4 z; z.x = 0; z.y = 0; z.z = 0; z.w = 0;
    *(uchar4*)(rf + zoff) = z;
    if (tid == 0) nrm[(size_t)lb * PPAD + p] = 0.0f;
    return;
  }
  const size_t outoff = ((size_t)lb * PPAD + p) * DD + rf_swz(p, d0);
  const float mu = mu_acc[lb] * (1.0f / ((float)PP * (float)DD));
  const int ph = p / PATCH_W, pw = p % PATCH_W;
  const int pad = r >> 1;
  float s0 = 0, s1 = 0, s2 = 0, s3 = 0;
  int cnt = 0;
  for (int dy = -pad; dy <= pad; dy++) {
    int qh = ph + dy; if (qh < 0 || qh >= PATCH_H) continue;
    for (int dx = -pad; dx <= pad; dx++) {
      int qw = pw + dx; if (qw < 0 || qw >= PATCH_W) continue;
      cnt++;
      const float* src = x + ((size_t)lb * PP + qh * PATCH_W + qw) * DD + d0;
      float4 u = *(const float4*)src;
      s0 += u.x; s1 += u.y; s2 += u.z; s3 += u.w;
    }
  }
  __shared__ float red[4];
  finish_r(s0, s1, s2, s3, (float)cnt * mu, rf + outoff,
           nrm + (size_t)lb * PPAD + p, tid, red);
}

// ---------------------------------------------------------------------------
// K3: per (rsel, l, pair i<j): S = rf_i @ rf_j^T (fp8, S = 256*dot).
// 128x128 tile, 4 waves x 2x2 MFMA_SCALE 32x32x64 fp8 (unit E8M0 scales ->
// bit-equivalent to plain fp8 dot, 2.3x the 16x16x32 instruction rate),
// BK=64, pre-swizzled rf (linear global_load_lds staging; ds_read_b64
// fragment reads compensate the swizzle -> conflict-free).
// Schedule: double-buffered LDS, counted s_waitcnt vmcnt(4) + raw s_barrier,
// XCD-chunk block swizzle (L2-resident pair panels).
// Fused epilogue: row/col max of (2S - n_other) via atomicMax(uint(v+1024)).
// grid (121*nz), block 256.
// __launch_bounds__(256, 1): R4/R5 post-mortem -- on this toolchain arg=3
// caps VGPRs at ~85 (512/(2*arg)); the scaled-MFMA kernel needs ~130-150
// (C/D in VGPRs), so arg=3 spilled ~64 regs/lane -> 20 GB scratch traffic
// and 4x regression.  arg=1 lets the allocator take what it needs; runtime
// occupancy still ~3 blocks/CU (512/~150 ~= 3 waves/SIMD).
__global__ __launch_bounds__(256, 1) void k3_pairdots(const unsigned char* __restrict__ rf,
                                                      const float* __restrict__ nrm,
                                                      unsigned int* __restrict__ mind) {
  // T1: XCD-chunk bijective swizzle (gridDim.x divisible by 8; chunks cover
  // whole pairs since 5082 = 42*121, 1694 = 14*121).
  const unsigned int cpx = gridDim.x >> 3;
  const unsigned int wid = (blockIdx.x & 7) * cpx + (blockIdx.x >> 3);
  const int z  = wid / 121;
  const int rm = wid % 121;
  const int ty = rm / 11;        // col tile
  const int tx = rm % 11;        // row tile

  const int rsel = z / ZPAIR;
  const int zz   = z % ZPAIR;
  const int l = zz / NPAIR;
  int rem = zz % NPAIR;
  int i = 0, span = BIMG - 1;
  while (rem >= span) { rem -= span; span--; i++; }
  const int j = i + 1 + rem;

  const unsigned char* rfr = rf + (size_t)rsel * RFSZ;
  const int rowbase = tx * 128;
  const int colbase = ty * 128;
  const unsigned char* A  = rfr + ((size_t)(l * BIMG + i) * PPAD + rowbase) * DD;
  const unsigned char* Bp = rfr + ((size_t)(l * BIMG + j) * PPAD + colbase) * DD;

  __shared__ __align__(16) unsigned char lA[2][128 * 64];  // 2 x 8 KB
  __shared__ __align__(16) unsigned char lB[2][128 * 64];

  const int tid  = threadIdx.x;
  const int lane = tid & 63;
  const int wave = tid >> 6;
  const int ls   = lane & 31;          // row within 32-row MFMA tile
  const int khg  = (lane >> 5) * 2;    // logical 16B-granule base of K-chunk
  const int gsw  = (ls >> 2) & 3;      // granule swizzle (matches rf_swz)
  const int hsw  = (ls >> 1) & 1;      // 8B-half swizzle
  // physical byte offsets (within the 64B LDS row) of the 4 logical 8B pieces
  const int off0 = ((khg ^ gsw) << 4)       | (hsw << 3);
  const int off1 = ((khg ^ gsw) << 4)       | ((1 ^ hsw) << 3);
  const int off2 = (((khg + 1) ^ gsw) << 4) | (hsw << 3);
  const int off3 = (((khg + 1) ^ gsw) << 4) | ((1 ^ hsw) << 3);

  const int wr = (wave >> 1) * 64;
  const int wc = (wave & 1) * 64;
  const int rA0 = (wr + ls) * 64,      rA1 = (wr + 32 + ls) * 64;
  const int rB0 = (wc + ls) * 64,      rB1 = (wc + 32 + ls) * 64;

  floatx16 acc[2][2];
#pragma unroll
  for (int a = 0; a < 2; a++)
#pragma unroll
    for (int b = 0; b < 2; b++)
#pragma unroll
      for (int r = 0; r < 16; r++) acc[a][b][r] = 0.0f;

  // staging: lane covers row = wave*32 + lane>>2 [+16], granule lane&3.
  // rf is pre-swizzled, so this is a plain linear copy.
  const int r0  = wave * 32 + (lane >> 2);
  const size_t goff = (size_t)r0 * DD + (lane & 3) * 16;   // same for A and B
  const int woff = wave * 2048;

  // prologue: stage tile 0 into buffer 0 (4 outstanding vm ops)
  gload_lds16(A + goff, lA[0] + woff);
  gload_lds16(A + goff + 16 * DD, lA[0] + woff + 1024);
  gload_lds16(Bp + goff, lB[0] + woff);
  gload_lds16(Bp + goff + 16 * DD, lB[0] + woff + 1024);

  for (int t = 0; t < 15; ++t) {
    const int cur = t & 1;
    // issue next tile's loads into the other buffer (outstanding -> 8)
    const int k1 = (t + 1) << 6;
    gload_lds16(A + goff + k1, lA[cur ^ 1] + woff);
    gload_lds16(A + goff + 16 * DD + k1, lA[cur ^ 1] + woff + 1024);
    gload_lds16(Bp + goff + k1, lB[cur ^ 1] + woff);
    gload_lds16(Bp + goff + 16 * DD + k1, lB[cur ^ 1] + woff + 1024);
    // counted wait: tile t's 4 loads landed; tile t+1's 4 keep flying
    asm volatile("s_waitcnt vmcnt(4)" ::: "memory");
    __builtin_amdgcn_s_barrier();          // all waves' tile-t data resident
    __builtin_amdgcn_sched_barrier(0);
    {
      const unsigned char* cA = lA[cur];
      const unsigned char* cB = lB[cur];
      intx8 a0 = loadfrag(cA, rA0, off0, off1, off2, off3);
      intx8 a1 = loadfrag(cA, rA1, off0, off1, off2, off3);
      intx8 b0 = loadfrag(cB, rB0, off0, off1, off2, off3);
      intx8 b1 = loadfrag(cB, rB1, off0, off1, off2, off3);
      acc[0][0] = __builtin_amdgcn_mfma_scale_f32_32x32x64_f8f6f4(
          a0, b0, acc[0][0], 0, 0, 0, MXSC, 0, MXSC);
      acc[0][1] = __builtin_amdgcn_mfma_scale_f32_32x32x64_f8f6f4(
          a0, b1, acc[0][1], 0, 0, 0, MXSC, 0, MXSC);
      acc[1][0] = __builtin_amdgcn_mfma_scale_f32_32x32x64_f8f6f4(
          a1, b0, acc[1][0], 0, 0, 0, MXSC, 0, MXSC);
      acc[1][1] = __builtin_amdgcn_mfma_scale_f32_32x32x64_f8f6f4(
          a1, b1, acc[1][1], 0, 0, 0, MXSC, 0, MXSC);
    }
    __builtin_amdgcn_sched_barrier(0);
    __builtin_amdgcn_s_barrier();          // all waves done reading buf[cur]
  }
  // tail t=15: only its own 4 loads outstanding
  asm volatile("s_waitcnt vmcnt(0)" ::: "memory");
  __builtin_amdgcn_s_barrier();
  __builtin_amdgcn_sched_barrier(0);
  {
    const unsigned char* cA = lA[1];
    const unsigned char* cB = lB[1];
    intx8 a0 = loadfrag(cA, rA0, off0, off1, off2, off3);
    intx8 a1 = loadfrag(cA, rA1, off0, off1, off2, off3);
    intx8 b0 = loadfrag(cB, rB0, off0, off1, off2, off3);
    intx8 b1 = loadfrag(cB, rB1, off0, off1, off2, off3);
    acc[0][0] = __builtin_amdgcn_mfma_scale_f32_32x32x64_f8f6f4(
        a0, b0, acc[0][0], 0, 0, 0, MXSC, 0, MXSC);
    acc[0][1] = __builtin_amdgcn_mfma_scale_f32_32x32x64_f8f6f4(
        a0, b1, acc[0][1], 0, 0, 0, MXSC, 0, MXSC);
    acc[1][0] = __builtin_amdgcn_mfma_scale_f32_32x32x64_f8f6f4(
        a1, b0, acc[1][0], 0, 0, 0, MXSC, 0, MXSC);
    acc[1][1] = __builtin_amdgcn_mfma_scale_f32_32x32x64_f8f6f4(
        a1, b1, acc[1][1], 0, 0, 0, MXSC, 0, MXSC);
  }

  const float* nI = nrm + rsel * NRMSZ + (size_t)(l * BIMG + i) * PPAD;
  const float* nJ = nrm + rsel * NRMSZ + (size_t)(l * BIMG + j) * PPAD;
  unsigned int* mrow = mind + rsel * MINDSZ + ((size_t)(l * BIMG + i) * BIMG + j) * PP;
  unsigned int* mcol = mind + rsel * MINDSZ + ((size_t)(l * BIMG + j) * BIMG + i) * PP;

  const int rhalf = 4 * (lane >> 5);   // +4 row offset for upper lane half

  // row-max of (2S - n_j): C/D layout col=lane&31, row=(reg&3)+8*(reg>>2)+rhalf
#pragma unroll
  for (int mt = 0; mt < 2; mt++) {
#pragma unroll
    for (int reg = 0; reg < 16; reg++) {
      const int gr = rowbase + wr + mt * 32 + (reg & 3) + 8 * (reg >> 2) + rhalf;
      float v = -1e30f;
#pragma unroll
      for (int nt = 0; nt < 2; nt++) {
        const int gc = colbase + wc + nt * 32 + ls;
        if (gc < PP) v = fmaxf(v, 2.0f * acc[mt][nt][reg] - nJ[gc]);
      }
      for (int off = 1; off < 32; off <<= 1) v = fmaxf(v, __shfl_xor(v, off, 64));
      if (ls == 0 && gr < PP)
        atomicMax(mrow + gr, __float_as_uint(v + 1024.0f));
    }
  }
  // col-max of (2S - n_i)
#pragma unroll
  for (int nt = 0; nt < 2; nt++) {
    const int gc = colbase + wc + nt * 32 + ls;
    float v = -1e30f;
#pragma unroll
    for (int mt = 0; mt < 2; mt++) {
#pragma unroll
      for (int reg = 0; reg < 16; reg++) {
        const int gr = rowbase + wr + mt * 32 + (reg & 3) + 8 * (reg >> 2) + rhalf;
        if (gr < PP) v = fmaxf(v, 2.0f * acc[mt][nt][reg] - nI[gr]);
      }
    }
    v = fmaxf(v, __shfl_xor(v, 32, 64));
    if (lane < 32 && gc < PP)
      atomicMax(mcol + gc, __float_as_uint(v + 1024.0f));
  }
}

// ---------------------------------------------------------------------------
// K4: per (i,p): over nr r-buffers and L layers, d2=(n_own - max(2S-n_other))/256,
// dist=sqrt; mean of 2 smallest over b!=i; accumulate into scores.
__global__ void k4_scores(const unsigned int* __restrict__ mind,
                          const float* __restrict__ nrm,
                          float* __restrict__ scores, int nr) {
  const int idx = blockIdx.x * 256 + threadIdx.x;
  if (idx >= BIMG * PP) return;
  const int i = idx / PP, p = idx % PP;
  float accum = 0.0f;
  for (int r = 0; r < nr; r++) {
    for (int l = 0; l < L_LAYERS; l++) {
      const float n_own = nrm[r * NRMSZ + (size_t)(l * BIMG + i) * PPAD + p];
      float m1 = 1e30f, m2 = 1e30f;
      for (int b = 0; b < BIMG; b++) {
        if (b == i) continue;
        const unsigned int enc =
            mind[r * MINDSZ + ((size_t)(l * BIMG + i) * BIMG + b) * PP + p];
        const float val = __uint_as_float(enc) - 1024.0f;
        const float d2 = fmaxf((n_own - val) * (1.0f / 256.0f), 1e-12f);
        const float dist = sqrtf(d2);
        if (dist < m1) { m2 = m1; m1 = dist; }
        else if (dist < m2) { m2 = dist; }
      }
      accum += 0.5f * (m1 + m2);
    }
  }
  scores[idx] += accum * (1.0f / (float)(L_LAYERS * 3));
}

// ---------------------------------------------------------------------------
__global__ void k5_imgmax(const float* __restrict__ scores, float* __restrict__ img) {
  const int i = blockIdx.x;
  float m = -1e30f;
  for (int p = threadIdx.x; p < PP; p += 256) m = fmaxf(m, scores[i * PP + p]);
  for (int off = 1; off < 64; off <<= 1) m = fmaxf(m, __shfl_xor(m, off, 64));
  __shared__ float red[4];
  if ((threadIdx.x & 63) == 0) red[threadIdx.x >> 6] = m;
  __syncthreads();
  if (threadIdx.x == 0)
    img[i] = fmaxf(fmaxf(red[0], red[1]), fmaxf(red[2], red[3]));
}

// ---------------------------------------------------------------------------
__global__ void k6_final(const float* __restrict__ cls,
                         const float* __restrict__ img,
                         float* __restrict__ out) {
  __shared__ float norms[BIMG];
  __shared__ float sim[BIMG][BIMG];
  const int t = threadIdx.x;
  if (t < BIMG) {
    float s = 0;
    for (int d = 0; d < JJ; d++) { float v = cls[t * JJ + d]; s += v * v; }
    norms[t] = sqrtf(s);
  }
  __syncthreads();
  {
    const int ii = t >> 3, jj = t & 7;
    float s = 0;
    for (int d = 0; d < JJ; d++) s += cls[ii * JJ + d] * cls[jj * JJ + d];
    sim[ii][jj] = s / (norms[ii] * norms[jj]);
  }
  __syncthreads();
  if (t < BIMG) {
    float v[8]; int id[8];
    for (int a = 0; a < 8; a++) { v[a] = sim[t][a]; id[a] = a; }
    for (int a = 0; a < 8; a++) {
      int best = a;
      for (int b = a + 1; b < 8; b++) if (v[b] > v[best]) best = b;
      float tv = v[a]; v[a] = v[best]; v[best] = tv;
      int ti = id[a]; id[a] = id[best]; id[best] = ti;
    }
    float res = 0;
    for (int k = 1; k <= 3; k++) {
      float num = 0, den = 0;
      for (int a = 0; a < k; a++) { num += v[a] * img[id[a]]; den += v[a]; }
      res += num / den;
    }
    out[t] = res * (1.0f / 3.0f);
  }
}

// ---------------------------------------------------------------------------
__global__ void k7_pixel(const float* __restrict__ scores,
                         float* __restrict__ out) {
  const int idx = blockIdx.x * 256 + threadIdx.x;
  if (idx >= BIMG * HOUT * WOUT) return;
  const int b = idx / (HOUT * WOUT);
  const int rem = idx % (HOUT * WOUT);
  const int Y = rem / WOUT, X = rem % WOUT;
  const float sy = (float)(PATCH_H - 1) / (float)(HOUT - 1);
  const float sx = (float)(PATCH_W - 1) / (float)(WOUT - 1);
  float py = (float)Y * sy;
  float px = (float)X * sx;
  int y0 = (int)floorf(py); y0 = min(max(y0, 0), PATCH_H - 1);
  int x0 = (int)floorf(px); x0 = min(max(x0, 0), PATCH_W - 1);
  const int y1 = min(y0 + 1, PATCH_H - 1);
  const int x1 = min(x0 + 1, PATCH_W - 1);
  const float wy = py - (float)y0, wx = px - (float)x0;
  const float* sc = scores + (size_t)b * PP;
  const float v =
      (1.f - wy) * ((1.f - wx) * sc[y0 * PATCH_W + x0] + wx * sc[y0 * PATCH_W + x1]) +
      wy         * ((1.f - wx) * sc[y1 * PATCH_W + x0] + wx * sc[y1 * PATCH_W + x1]);
  out[8 + idx] = v;
}

// ---------------------------------------------------------------------------
extern "C" void kernel_launch(void* const* d_in, const int* in_sizes, int n_in,
                              void* d_out, int out_size, void* d_ws, size_t ws_size,
                              hipStream_t stream) {
  const float* feat = (const float*)d_in[0];  // (4,8,1369,1024) f32
  const float* cls  = (const float*)d_in[1];  // (8,768) f32
  float* out = (float*)d_out;

  const size_t need_fused = 3 * RFSZ + 3 * MINDSZ * 4 + 3 * NRMSZ * 4 +
                            (size_t)BIMG * PP * 4 + 1024;
  const bool fused = ws_size >= need_fused;

  char* ws = (char*)d_ws;
  size_t off = 0;
  unsigned char* rf = (unsigned char*)(ws + off);
  off += (fused ? 3 : 1) * RFSZ;
  unsigned int* mind = (unsigned int*)(ws + off);
  off += (fused ? 3 : 1) * MINDSZ * 4;
  float* nrm = (float*)(ws + off);
  off += (fused ? 3 : 1) * NRMSZ * 4;
  float* scores = (float*)(ws + off);
  off += (size_t)BIMG * PP * 4;
  float* mu_acc = (float*)(ws + off);
  off += 32 * 4;
  float* img = (float*)(ws + off);
  off += 8 * 4;

  hipMemsetAsync(mu_acc, 0, 32 * 4, stream);
  hipMemsetAsync(scores, 0, (size_t)BIMG * PP * 4, stream);
  k1_mu<<<dim3(43, 32), 256, 0, stream>>>(feat, mu_acc);

  if (fused) {
    k2_pool3<<<dim3(PPAD, 32), 256, 0, stream>>>(feat, mu_acc, rf, nrm);
    hipMemsetAsync(mind, 0, 3 * MINDSZ * 4, stream);
    k3_pairdots<<<dim3(121 * 3 * ZPAIR), 256, 0, stream>>>(rf, nrm, mind);
    k4_scores<<<(BIMG * PP + 255) / 256, 256, 0, stream>>>(mind, nrm, scores, 3);
  } else {
    const int rlist[3] = {1, 3, 5};
    for (int ri = 0; ri < 3; ri++) {
      k2_pool<<<dim3(PPAD, 32), 256, 0, stream>>>(feat, mu_acc, rf, nrm, rlist[ri]);
      hipMemsetAsync(mind, 0, MINDSZ * 4, stream);
      k3_pairdots<<<dim3(121 * ZPAIR), 256, 0, stream>>>(rf, nrm, mind);
      k4_scores<<<(BIMG * PP + 255) / 256, 256, 0, stream>>>(mind, nrm, scores, 1);
    }
  }
  k5_imgmax<<<8, 256, 0, stream>>>(scores, img);
  k6_final<<<1, 64, 0, stream>>>(cls, img, out);
  k7_pixel<<<(BIMG * HOUT * WOUT + 255) / 256, 256, 0, stream>>>(scores, out);
}

// Round 7
// 2387.454 us; speedup vs baseline: 3.1869x; 2.3293x over previous
//
#include <hip/hip_runtime.h>
#include <hip/hip_bf16.h>
#include <math.h>

#define L_LAYERS 4
#define BIMG 8
#define PATCH_H 37
#define PATCH_W 37
#define PP 1369
#define DD 1024
#define JJ 768
#define HOUT 518
#define WOUT 518
#define PPAD 1408   // 11 * 128
#define NPAIR 28
#define ZPAIR (L_LAYERS * NPAIR)          // 112
#define RFSZ  ((size_t)L_LAYERS * BIMG * PPAD * DD)    // bytes (fp8) = 46,137,344
#define NRMSZ ((size_t)L_LAYERS * BIMG * PPAD)         // floats
#define MINDSZ ((size_t)L_LAYERS * BIMG * BIMG * PP)   // uints

typedef float floatx4 __attribute__((ext_vector_type(4)));

// ---- software OCP e4m3fn encode/decode (RTNE) ------------------------------
__device__ __forceinline__ unsigned int f2e4m3(float v) {
  unsigned int b = __float_as_uint(v);
  unsigned int sign = (b >> 24) & 0x80u;
  float mag = fabsf(v);
  unsigned int code;
  if (mag >= 0.015625f) {                       // normal (exp >= -6)
    unsigned int mb = __float_as_uint(mag);
    mb = mb + 0x0007ffffu + ((mb >> 20) & 1u);  // RTNE to 3 mantissa bits
    code = (((mb >> 23) - 120u) << 3) | ((mb >> 20) & 7u);
  } else {                                      // denormal: quantum 2^-9
    code = (unsigned int)__float2int_rn(mag * 512.0f);
  }
  return code | sign;
}
__device__ __forceinline__ float e4m3tof(unsigned int c) {
  unsigned int em = c & 0x7fu;
  float m;
  if (em >= 8u) m = __uint_as_float((((em >> 3) + 120u) << 23) | ((em & 7u) << 20));
  else          m = (float)em * 0.001953125f;
  return (c & 0x80u) ? -m : m;
}

// rf physical byte swizzle, baked at store time:
// within each 64B K-chunk of patch-row p:  granule g (16B) -> g ^ ((p>>2)&3),
// half h (8B) -> h ^ ((p>>1)&1).  Makes K3's ds_read_b64 bank-conflict-free
// (16 distinct bank-pairs per 16-lane phase) with a LINEAR global_load_lds.
__device__ __forceinline__ int rf_swz(int p, int d) {
  return (d & ~63) |
         ((((d >> 4) & 3) ^ ((p >> 2) & 3)) << 4) |
         ((((d >> 3) & 1) ^ ((p >> 1) & 1)) << 3) |
         (d & 7);
}

// async global->LDS, 16B per lane; LDS dest = wave-uniform base + lane*16
__device__ __forceinline__ void gload_lds16(const void* gptr, void* lptr) {
  __builtin_amdgcn_global_load_lds(
      (const __attribute__((address_space(1))) unsigned int*)gptr,
      (__attribute__((address_space(3))) unsigned int*)lptr, 16, 0, 0);
}

// ---------------------------------------------------------------------------
// K1: per-(l,b) mean of features (float32).  grid (43, 32), block 256.
__global__ __launch_bounds__(256) void k1_mu(const float* __restrict__ x,
                                             float* __restrict__ mu_acc) {
  const int lb = blockIdx.y;
  const float* base = x + (size_t)lb * PP * DD;
  const int N4 = PP * DD / 4;
  float s = 0.0f;
  for (int idx = blockIdx.x * 256 + threadIdx.x; idx < N4; idx += gridDim.x * 256) {
    float4 u = *(const float4*)(base + (size_t)idx * 4);
    s += u.x + u.y + u.z + u.w;
  }
  for (int off = 1; off < 64; off <<= 1) s += __shfl_xor(s, off, 64);
  __shared__ float red[4];
  if ((threadIdx.x & 63) == 0) red[threadIdx.x >> 6] = s;
  __syncthreads();
  if (threadIdx.x == 0)
    atomicAdd(&mu_acc[lb], red[0] + red[1] + red[2] + red[3]);
}

// ---------------------------------------------------------------------------
// shared finisher: subtract cnt*mu, block-L2-normalize, x16, fp8-encode, store
__device__ __forceinline__ void finish_r(float s0, float s1, float s2, float s3,
                                         float cm, unsigned char* dst, float* nrmdst,
                                         int tid, float* red) {
  s0 -= cm; s1 -= cm; s2 -= cm; s3 -= cm;
  float sq = s0 * s0 + s1 * s1 + s2 * s2 + s3 * s3;
  for (int off = 1; off < 64; off <<= 1) sq += __shfl_xor(sq, off, 64);
  __syncthreads();
  if ((tid & 63) == 0) red[tid >> 6] = sq;
  __syncthreads();
  const float rn16 = rsqrtf(red[0] + red[1] + red[2] + red[3]) * 16.0f;
  unsigned int c0 = f2e4m3(s0 * rn16), c1 = f2e4m3(s1 * rn16);
  unsigned int c2 = f2e4m3(s2 * rn16), c3 = f2e4m3(s3 * rn16);
  uchar4 o; o.x = (unsigned char)c0; o.y = (unsigned char)c1;
  o.z = (unsigned char)c2; o.w = (unsigned char)c3;
  *(uchar4*)dst = o;
  float q0 = e4m3tof(c0), q1 = e4m3tof(c1), q2 = e4m3tof(c2), q3 = e4m3tof(c3);
  float nq = q0 * q0 + q1 * q1 + q2 * q2 + q3 * q3;
  for (int off = 1; off < 64; off <<= 1) nq += __shfl_xor(nq, off, 64);
  __syncthreads();
  if ((tid & 63) == 0) red[tid >> 6] = nq;
  __syncthreads();
  if (tid == 0) *nrmdst = red[0] + red[1] + red[2] + red[3];
}

// K2f: fused pool for r=1,3,5 from one 5x5 read.  grid (PPAD, 32), block 256.
__global__ __launch_bounds__(256) void k2_pool3(const float* __restrict__ x,
                                                const float* __restrict__ mu_acc,
                                                unsigned char* __restrict__ rf,
                                                float* __restrict__ nrm) {
  const int p  = blockIdx.x;
  const int lb = blockIdx.y;
  const int tid = threadIdx.x;
  const int d0 = tid * 4;
  if (p >= PP) {
    const size_t zoff = ((size_t)lb * PPAD + p) * DD + d0;
    uchar4 z; z.x = 0; z.y = 0; z.z = 0; z.w = 0;
    for (int r = 0; r < 3; r++) {
      *(uchar4*)(rf + r * RFSZ + zoff) = z;
      if (tid == 0) nrm[r * NRMSZ + (size_t)lb * PPAD + p] = 0.0f;
    }
    return;
  }
  // store at physical (bank-swizzled) offset
  const size_t outoff = ((size_t)lb * PPAD + p) * DD + rf_swz(p, d0);
  const float mu = mu_acc[lb] * (1.0f / ((float)PP * (float)DD));
  const int ph = p / PATCH_W, pw = p % PATCH_W;
  float a5[4] = {0, 0, 0, 0}, a3[4] = {0, 0, 0, 0}, a1[4] = {0, 0, 0, 0};
  int c5 = 0, c3 = 0;
  for (int dy = -2; dy <= 2; dy++) {
    int qh = ph + dy; if (qh < 0 || qh >= PATCH_H) continue;
    for (int dx = -2; dx <= 2; dx++) {
      int qw = pw + dx; if (qw < 0 || qw >= PATCH_W) continue;
      const float* src = x + ((size_t)lb * PP + qh * PATCH_W + qw) * DD + d0;
      float4 u = *(const float4*)src;
      a5[0] += u.x; a5[1] += u.y; a5[2] += u.z; a5[3] += u.w; c5++;
      if (dy >= -1 && dy <= 1 && dx >= -1 && dx <= 1) {
        a3[0] += u.x; a3[1] += u.y; a3[2] += u.z; a3[3] += u.w; c3++;
        if (dy == 0 && dx == 0) { a1[0] = u.x; a1[1] = u.y; a1[2] = u.z; a1[3] = u.w; }
      }
    }
  }
  __shared__ float red[4];
  const size_t noff = (size_t)lb * PPAD + p;
  finish_r(a1[0], a1[1], a1[2], a1[3], mu, rf + outoff, nrm + noff, tid, red);
  finish_r(a3[0], a3[1], a3[2], a3[3], (float)c3 * mu, rf + RFSZ + outoff,
           nrm + NRMSZ + noff, tid, red);
  finish_r(a5[0], a5[1], a5[2], a5[3], (float)c5 * mu, rf + 2 * RFSZ + outoff,
           nrm + 2 * NRMSZ + noff, tid, red);
}

// K2s: single-r pool (fallback path).  grid (PPAD, 32), block 256.
__global__ __launch_bounds__(256) void k2_pool(const float* __restrict__ x,
                                               const float* __restrict__ mu_acc,
                                               unsigned char* __restrict__ rf,
                                               float* __restrict__ nrm, int r) {
  const int p  = blockIdx.x;
  const int lb = blockIdx.y;
  const int tid = threadIdx.x;
  const int d0 = tid * 4;
  if (p >= PP) {
    const size_t zoff = ((size_t)lb * PPAD + p) * DD + d0;
    uchar4 z; z.x = 0; z.y = 0; z.z = 0; z.w = 0;
    *(uchar4*)(rf + zoff) = z;
    if (tid == 0) nrm[(size_t)lb * PPAD + p] = 0.0f;
    return;
  }
  const size_t outoff = ((size_t)lb * PPAD + p) * DD + rf_swz(p, d0);
  const float mu = mu_acc[lb] * (1.0f / ((float)PP * (float)DD));
  const int ph = p / PATCH_W, pw = p % PATCH_W;
  const int pad = r >> 1;
  float s0 = 0, s1 = 0, s2 = 0, s3 = 0;
  int cnt = 0;
  for (int dy = -pad; dy <= pad; dy++) {
    int qh = ph + dy; if (qh < 0 || qh >= PATCH_H) continue;
    for (int dx = -pad; dx <= pad; dx++) {
      int qw = pw + dx; if (qw < 0 || qw >= PATCH_W) continue;
      cnt++;
      const float* src = x + ((size_t)lb * PP + qh * PATCH_W + qw) * DD + d0;
      float4 u = *(const float4*)src;
      s0 += u.x; s1 += u.y; s2 += u.z; s3 += u.w;
    }
  }
  __shared__ float red[4];
  finish_r(s0, s1, s2, s3, (float)cnt * mu, rf + outoff,
           nrm + (size_t)lb * PPAD + p, tid, red);
}

// ---------------------------------------------------------------------------
// K3: per (rsel, l, pair i<j): S = rf_i @ rf_j^T (fp8, S = 256*dot).
// 128x128 tile, 4 waves x 4x4 MFMA 16x16x32 fp8, BK=64, pre-swizzled rf
// (linear global_load_lds staging, conflict-free ds_read_b64).  [R3-verified
// MFMA/fragment/epilogue code; R4-R6's MX detour reverted -- MFMA pipe was
// only 35% busy, so a faster MFMA instruction was raising a non-binding
// ceiling at catastrophic register cost.]
// Schedule (R7): ONE barrier per K-step.  Order: wait vmcnt(0) -> s_barrier
// -> stage tile t+1 into buf[cur^1] -> compute buf[cur].  The single barrier
// serves both roles: publishes tile t (each wave drained its own loads
// first) and certifies all waves finished reading buf[cur^1] at iter t-1
// (safe to restage).  The vmcnt(0) is cheap: those loads had the entire
// previous compute phase to land (L2-resident via XCD swizzle).
// Barriers: 31 -> 16 vs R3.  grid (121*nz), block 256, 4 blk/CU.
__global__ __launch_bounds__(256, 4) void k3_pairdots(const unsigned char* __restrict__ rf,
                                                      const float* __restrict__ nrm,
                                                      unsigned int* __restrict__ mind) {
  // T1: XCD-chunk bijective swizzle (gridDim.x divisible by 8; chunks cover
  // whole pairs since 5082 = 42*121, 1694 = 14*121).
  const unsigned int cpx = gridDim.x >> 3;
  const unsigned int wid = (blockIdx.x & 7) * cpx + (blockIdx.x >> 3);
  const int z  = wid / 121;
  const int rm = wid % 121;
  const int ty = rm / 11;        // col tile
  const int tx = rm % 11;        // row tile

  const int rsel = z / ZPAIR;
  const int zz   = z % ZPAIR;
  const int l = zz / NPAIR;
  int rem = zz % NPAIR;
  int i = 0, span = BIMG - 1;
  while (rem >= span) { rem -= span; span--; i++; }
  const int j = i + 1 + rem;

  const unsigned char* rfr = rf + (size_t)rsel * RFSZ;
  const int rowbase = tx * 128;
  const int colbase = ty * 128;
  const unsigned char* A  = rfr + ((size_t)(l * BIMG + i) * PPAD + rowbase) * DD;
  const unsigned char* Bp = rfr + ((size_t)(l * BIMG + j) * PPAD + colbase) * DD;

  __shared__ __align__(16) unsigned char lA[2][128 * 64];  // 2 x 8 KB
  __shared__ __align__(16) unsigned char lB[2][128 * 64];

  const int tid  = threadIdx.x;
  const int lane = tid & 63;
  const int wave = tid >> 6;
  const int lrow = lane & 15;
  const int quad = lane >> 4;
  const int wr = (wave >> 1) * 64;
  const int wc = (wave & 1) * 64;

  floatx4 acc[4][4];
#pragma unroll
  for (int a = 0; a < 4; a++)
#pragma unroll
    for (int b = 0; b < 4; b++) acc[a][b] = (floatx4){0.f, 0.f, 0.f, 0.f};

  // staging: lane covers row = wave*32 + lane>>2 [+16], granule lane&3.
  // rf is pre-swizzled, so this is a plain linear copy.
  const int r0  = wave * 32 + (lane >> 2);
  const size_t goff = (size_t)r0 * DD + (lane & 3) * 16;   // same for A and B
  const int woff = wave * 2048;

  // fragment-read swizzle terms (must match rf_swz with p bits = lrow bits)
  const int gs   = (lrow >> 2) & 3;          // 16B-granule XOR
  const int hb   = (lrow >> 1) & 1;          // 8B-half XOR
  const int sub8 = (((quad & 1) ^ hb) << 3);

  // prologue: stage tile 0 into buffer 0 (4 outstanding vm ops)
  gload_lds16(A + goff, lA[0] + woff);
  gload_lds16(A + goff + 16 * DD, lA[0] + woff + 1024);
  gload_lds16(Bp + goff, lB[0] + woff);
  gload_lds16(Bp + goff + 16 * DD, lB[0] + woff + 1024);

  for (int t = 0; t < 16; ++t) {
    const int cur = t & 1;
    // each wave drains its OWN tile-t loads, then the barrier certifies
    // (a) tile t fully resident (all waves drained) and (b) all waves done
    // reading buf[cur^1] from iter t-1 -> safe to restage it.
    asm volatile("s_waitcnt vmcnt(0)" ::: "memory");
    __builtin_amdgcn_s_barrier();
    __builtin_amdgcn_sched_barrier(0);
    if (t < 15) {
      const int k1 = (t + 1) << 6;
      gload_lds16(A + goff + k1, lA[cur ^ 1] + woff);
      gload_lds16(A + goff + 16 * DD + k1, lA[cur ^ 1] + woff + 1024);
      gload_lds16(Bp + goff + k1, lB[cur ^ 1] + woff);
      gload_lds16(Bp + goff + 16 * DD + k1, lB[cur ^ 1] + woff + 1024);
    }
    // compute tile t from buf[cur]; staged loads fly underneath
#pragma unroll
    for (int ks = 0; ks < 2; ks++) {
      const int gfrag = ((((ks << 1) + (quad >> 1)) ^ gs) << 4) + sub8;
      long af[4], bfv[4];
#pragma unroll
      for (int mt = 0; mt < 4; mt++)
        af[mt] = *(const long*)(lA[cur] + (wr + mt * 16 + lrow) * 64 + gfrag);
#pragma unroll
      for (int ct = 0; ct < 4; ct++)
        bfv[ct] = *(const long*)(lB[cur] + (wc + ct * 16 + lrow) * 64 + gfrag);
#pragma unroll
      for (int mt = 0; mt < 4; mt++)
#pragma unroll
        for (int ct = 0; ct < 4; ct++)
          acc[mt][ct] = __builtin_amdgcn_mfma_f32_16x16x32_fp8_fp8(
              af[mt], bfv[ct], acc[mt][ct], 0, 0, 0);
    }
    __builtin_amdgcn_sched_barrier(0);
  }

  const float* nI = nrm + rsel * NRMSZ + (size_t)(l * BIMG + i) * PPAD;
  const float* nJ = nrm + rsel * NRMSZ + (size_t)(l * BIMG + j) * PPAD;
  unsigned int* mrow = mind + rsel * MINDSZ + ((size_t)(l * BIMG + i) * BIMG + j) * PP;
  unsigned int* mcol = mind + rsel * MINDSZ + ((size_t)(l * BIMG + j) * BIMG + i) * PP;

  // row-max of (2S - n_j)
#pragma unroll
  for (int mt = 0; mt < 4; mt++) {
#pragma unroll
    for (int reg = 0; reg < 4; reg++) {
      const int gr = rowbase + wr + mt * 16 + quad * 4 + reg;
      float v = -1e30f;
#pragma unroll
      for (int ct = 0; ct < 4; ct++) {
        const int gc = colbase + wc + ct * 16 + lrow;
        if (gc < PP) v = fmaxf(v, 2.0f * acc[mt][ct][reg] - nJ[gc]);
      }
      for (int off = 1; off < 16; off <<= 1) v = fmaxf(v, __shfl_xor(v, off, 64));
      if (lrow == 0 && gr < PP)
        atomicMax(mrow + gr, __float_as_uint(v + 1024.0f));
    }
  }
  // col-max of (2S - n_i)
#pragma unroll
  for (int ct = 0; ct < 4; ct++) {
    const int gc = colbase + wc + ct * 16 + lrow;
    float v = -1e30f;
#pragma unroll
    for (int mt = 0; mt < 4; mt++) {
      const int grb = rowbase + wr + mt * 16 + quad * 4;
#pragma unroll
      for (int reg = 0; reg < 4; reg++)
        if (grb + reg < PP) v = fmaxf(v, 2.0f * acc[mt][ct][reg] - nI[grb + reg]);
    }
    for (int off = 16; off < 64; off <<= 1) v = fmaxf(v, __shfl_xor(v, off, 64));
    if (quad == 0 && gc < PP)
      atomicMax(mcol + gc, __float_as_uint(v + 1024.0f));
  }
}

// ---------------------------------------------------------------------------
// K4: per (i,p): over nr r-buffers and L layers, d2=(n_own - max(2S-n_other))/256,
// dist=sqrt; mean of 2 smallest over b!=i; accumulate into scores.
__global__ void k4_scores(const unsigned int* __restrict__ mind,
                          const float* __restrict__ nrm,
                          float* __restrict__ scores, int nr) {
  const int idx = blockIdx.x * 256 + threadIdx.x;
  if (idx >= BIMG * PP) return;
  const int i = idx / PP, p = idx % PP;
  float accum = 0.0f;
  for (int r = 0; r < nr; r++) {
    for (int l = 0; l < L_LAYERS; l++) {
      const float n_own = nrm[r * NRMSZ + (size_t)(l * BIMG + i) * PPAD + p];
      float m1 = 1e30f, m2 = 1e30f;
      for (int b = 0; b < BIMG; b++) {
        if (b == i) continue;
        const unsigned int enc =
            mind[r * MINDSZ + ((size_t)(l * BIMG + i) * BIMG + b) * PP + p];
        const float val = __uint_as_float(enc) - 1024.0f;
        const float d2 = fmaxf((n_own - val) * (1.0f / 256.0f), 1e-12f);
        const float dist = sqrtf(d2);
        if (dist < m1) { m2 = m1; m1 = dist; }
        else if (dist < m2) { m2 = dist; }
      }
      accum += 0.5f * (m1 + m2);
    }
  }
  scores[idx] += accum * (1.0f / (float)(L_LAYERS * 3));
}

// ---------------------------------------------------------------------------
__global__ void k5_imgmax(const float* __restrict__ scores, float* __restrict__ img) {
  const int i = blockIdx.x;
  float m = -1e30f;
  for (int p = threadIdx.x; p < PP; p += 256) m = fmaxf(m, scores[i * PP + p]);
  for (int off = 1; off < 64; off <<= 1) m = fmaxf(m, __shfl_xor(m, off, 64));
  __shared__ float red[4];
  if ((threadIdx.x & 63) == 0) red[threadIdx.x >> 6] = m;
  __syncthreads();
  if (threadIdx.x == 0)
    img[i] = fmaxf(fmaxf(red[0], red[1]), fmaxf(red[2], red[3]));
}

// ---------------------------------------------------------------------------
__global__ void k6_final(const float* __restrict__ cls,
                         const float* __restrict__ img,
                         float* __restrict__ out) {
  __shared__ float norms[BIMG];
  __shared__ float sim[BIMG][BIMG];
  const int t = threadIdx.x;
  if (t < BIMG) {
    float s = 0;
    for (int d = 0; d < JJ; d++) { float v = cls[t * JJ + d]; s += v * v; }
    norms[t] = sqrtf(s);
  }
  __syncthreads();
  {
    const int ii = t >> 3, jj = t & 7;
    float s = 0;
    for (int d = 0; d < JJ; d++) s += cls[ii * JJ + d] * cls[jj * JJ + d];
    sim[ii][jj] = s / (norms[ii] * norms[jj]);
  }
  __syncthreads();
  if (t < BIMG) {
    float v[8]; int id[8];
    for (int a = 0; a < 8; a++) { v[a] = sim[t][a]; id[a] = a; }
    for (int a = 0; a < 8; a++) {
      int best = a;
      for (int b = a + 1; b < 8; b++) if (v[b] > v[best]) best = b;
      float tv = v[a]; v[a] = v[best]; v[best] = tv;
      int ti = id[a]; id[a] = id[best]; id[best] = ti;
    }
    float res = 0;
    for (int k = 1; k <= 3; k++) {
      float num = 0, den = 0;
      for (int a = 0; a < k; a++) { num += v[a] * img[id[a]]; den += v[a]; }
      res += num / den;
    }
    out[t] = res * (1.0f / 3.0f);
  }
}

// ---------------------------------------------------------------------------
__global__ void k7_pixel(const float* __restrict__ scores,
                         float* __restrict__ out) {
  const int idx = blockIdx.x * 256 + threadIdx.x;
  if (idx >= BIMG * HOUT * WOUT) return;
  const int b = idx / (HOUT * WOUT);
  const int rem = idx % (HOUT * WOUT);
  const int Y = rem / WOUT, X = rem % WOUT;
  const float sy = (float)(PATCH_H - 1) / (float)(HOUT - 1);
  const float sx = (float)(PATCH_W - 1) / (float)(WOUT - 1);
  float py = (float)Y * sy;
  float px = (float)X * sx;
  int y0 = (int)floorf(py); y0 = min(max(y0, 0), PATCH_H - 1);
  int x0 = (int)floorf(px); x0 = min(max(x0, 0), PATCH_W - 1);
  const int y1 = min(y0 + 1, PATCH_H - 1);
  const int x1 = min(x0 + 1, PATCH_W - 1);
  const float wy = py - (float)y0, wx = px - (float)x0;
  const float* sc = scores + (size_t)b * PP;
  const float v =
      (1.f - wy) * ((1.f - wx) * sc[y0 * PATCH_W + x0] + wx * sc[y0 * PATCH_W + x1]) +
      wy         * ((1.f - wx) * sc[y1 * PATCH_W + x0] + wx * sc[y1 * PATCH_W + x1]);
  out[8 + idx] = v;
}

// ---------------------------------------------------------------------------
extern "C" void kernel_launch(void* const* d_in, const int* in_sizes, int n_in,
                              void* d_out, int out_size, void* d_ws, size_t ws_size,
                              hipStream_t stream) {
  const float* feat = (const float*)d_in[0];  // (4,8,1369,1024) f32
  const float* cls  = (const float*)d_in[1];  // (8,768) f32
  float* out = (float*)d_out;

  const size_t need_fused = 3 * RFSZ + 3 * MINDSZ * 4 + 3 * NRMSZ * 4 +
                            (size_t)BIMG * PP * 4 + 1024;
  const bool fused = ws_size >= need_fused;

  char* ws = (char*)d_ws;
  size_t off = 0;
  unsigned char* rf = (unsigned char*)(ws + off);
  off += (fused ? 3 : 1) * RFSZ;
  unsigned int* mind = (unsigned int*)(ws + off);
  off += (fused ? 3 : 1) * MINDSZ * 4;
  float* nrm = (float*)(ws + off);
  off += (fused ? 3 : 1) * NRMSZ * 4;
  float* scores = (float*)(ws + off);
  off += (size_t)BIMG * PP * 4;
  float* mu_acc = (float*)(ws + off);
  off += 32 * 4;
  float* img = (float*)(ws + off);
  off += 8 * 4;

  hipMemsetAsync(mu_acc, 0, 32 * 4, stream);
  hipMemsetAsync(scores, 0, (size_t)BIMG * PP * 4, stream);
  k1_mu<<<dim3(43, 32), 256, 0, stream>>>(feat, mu_acc);

  if (fused) {
    k2_pool3<<<dim3(PPAD, 32), 256, 0, stream>>>(feat, mu_acc, rf, nrm);
    hipMemsetAsync(mind, 0, 3 * MINDSZ * 4, stream);
    k3_pairdots<<<dim3(121 * 3 * ZPAIR), 256, 0, stream>>>(rf, nrm, mind);
    k4_scores<<<(BIMG * PP + 255) / 256, 256, 0, stream>>>(mind, nrm, scores, 3);
  } else {
    const int rlist[3] = {1, 3, 5};
    for (int ri = 0; ri < 3; ri++) {
      k2_pool<<<dim3(PPAD, 32), 256, 0, stream>>>(feat, mu_acc, rf, nrm, rlist[ri]);
      hipMemsetAsync(mind, 0, MINDSZ * 4, stream);
      k3_pairdots<<<dim3(121 * ZPAIR), 256, 0, stream>>>(rf, nrm, mind);
      k4_scores<<<(BIMG * PP + 255) / 256, 256, 0, stream>>>(mind, nrm, scores, 1);
    }
  }
  k5_imgmax<<<8, 256, 0, stream>>>(scores, img);
  k6_final<<<1, 64, 0, stream>>>(cls, img, out);
  k7_pixel<<<(BIMG * HOUT * WOUT + 255) / 256, 256, 0, stream>>>(scores, out);
}